// Round 17
// baseline (326.810 us; speedup 1.0000x reference)
//
#include <hip/hip_runtime.h>
#include <hip/hip_bf16.h>

#define H_DIM 1024
#define I_DIM 2048
#define NEXP  16
#define NTOK  4096
#define BK 32

// small-tile (fallback) geometry
#define BM 128
#define BN 128
#define ABUF (BM*BK)
#define BBUF (BN*BK)

// big-tile geometry (full path)
#define BM2 256
#define BN2 256
#define MAXS 12288                   // 8192 + 16*255 rounded up (256-align worst case)
#define MAXRB1 (MAXS/BM)             // 96 (fallback row blocks)
#define MAXRB2 (MAXS/BM2)            // 48
#define NC1 (I_DIM/BN)               // 16
#define NC2 (H_DIM/BN)               // 8
#define NC1B (I_DIM/BN2)             // 8
#define NC2B (H_DIM/BN2)             // 4

#define PAIRS (NTOK*2)
#define SORT_T 256
#define PPT (PAIRS/SORT_T)

typedef __attribute__((ext_vector_type(8))) short short8;
typedef __attribute__((ext_vector_type(4))) short short4v;
typedef __attribute__((ext_vector_type(4))) float f32x4;

// ws layout (bytes)
#define OFF_TOKE 256
#define OFF_TOKW (OFF_TOKE + PAIRS*4)                        // 33024
#define OFF_TOS  (OFF_TOKW + PAIRS*4)                        // 65792
#define OFF_WOS  (OFF_TOS + MAXS*4)                          // 114944
#define OFF_H    (OFF_WOS + MAXS*4)                          // 164096
#define OFF_XBF  (OFF_H + (size_t)MAXS*I_DIM*2)              // 50495744
#define OFF_WBF  (OFF_XBF + (size_t)NTOK*H_DIM*2)            // 58884352
#define NEED_XBF OFF_WBF
#define NEED_FULL (OFF_WBF + (size_t)NEXP*I_DIM*H_DIM*2)     // 125993216

#define GLDS16(gsrc, ldst) \
  __builtin_amdgcn_global_load_lds((const __attribute__((address_space(1))) void*)(gsrc), \
                                   (__attribute__((address_space(3))) void*)(ldst), 16, 0, 0)

__device__ inline short f2bf(float f) {
    union { float f; unsigned u; } v; v.f = f;
    unsigned u = v.u + 0x7FFFu + ((v.u >> 16) & 1u);   // RNE
    return (short)(u >> 16);
}

__device__ inline short8 pack8(const float4 a, const float4 b) {
    return (short8){ f2bf(a.x), f2bf(a.y), f2bf(a.z), f2bf(a.w),
                     f2bf(b.x), f2bf(b.y), f2bf(b.z), f2bf(b.w) };
}

__device__ inline int xcd_swz(int bid, int nwg) {
    return (bid & 7) * (nwg >> 3) + (bid >> 3);
}

// ---------------- fp32 -> bf16 streaming convert ----------------
__global__ __launch_bounds__(256) void conv_kernel(
    const float* __restrict__ src, short* __restrict__ dst, int n8)
{
    int i = blockIdx.x * blockDim.x + threadIdx.x;
    const int stride = gridDim.x * blockDim.x;
    for (; i < n8; i += stride) {
        const float4 f0 = ((const float4*)src)[2*i];
        const float4 f1 = ((const float4*)src)[2*i+1];
        ((short8*)dst)[i] = pack8(f0, f1);
    }
}

// ---------------- gate: one wave per token; optionally emits x in bf16 ----------------
template<bool WRITE_XBF>
__global__ __launch_bounds__(256) void gate_kernel(
    const float* __restrict__ x, const float* __restrict__ Wg,
    int* __restrict__ tokE, float* __restrict__ tokW, short* __restrict__ xbf)
{
    const int tok  = blockIdx.x * 4 + (threadIdx.x >> 6);
    const int lane = threadIdx.x & 63;
    const float4* xr = (const float4*)(x + (size_t)tok * H_DIM);

    float acc[NEXP];
#pragma unroll
    for (int e = 0; e < NEXP; e++) acc[e] = 0.f;
#pragma unroll
    for (int j = 0; j < H_DIM/4; j += 64) {
        const float4 xv = xr[j + lane];
        if constexpr (WRITE_XBF) {
            *(short4v*)(xbf + (size_t)tok * H_DIM + (j + lane) * 4) =
                (short4v){ f2bf(xv.x), f2bf(xv.y), f2bf(xv.z), f2bf(xv.w) };
        }
#pragma unroll
        for (int e = 0; e < NEXP; e++) {
            const float4 wv = ((const float4*)(Wg + e * H_DIM))[j + lane];
            acc[e] = fmaf(xv.x, wv.x, fmaf(xv.y, wv.y, fmaf(xv.z, wv.z, fmaf(xv.w, wv.w, acc[e]))));
        }
    }
#pragma unroll
    for (int off = 32; off; off >>= 1) {
#pragma unroll
        for (int e = 0; e < NEXP; e++) acc[e] += __shfl_xor(acc[e], off, 64);
    }
    if (lane == 0) {
        float m = acc[0];
#pragma unroll
        for (int e = 1; e < NEXP; e++) m = fmaxf(m, acc[e]);
        float p[NEXP]; float s = 0.f;
#pragma unroll
        for (int e = 0; e < NEXP; e++) { p[e] = __expf(acc[e] - m); s += p[e]; }
        int i1 = 0;
#pragma unroll
        for (int e = 1; e < NEXP; e++) if (acc[e] > acc[i1]) i1 = e;
        int i2 = -1;
#pragma unroll
        for (int e = 0; e < NEXP; e++) {
            if (e == i1) continue;
            if (i2 < 0 || acc[e] > acc[i2]) i2 = e;
        }
        const float inv = 1.f / s;
        tokE[tok*2+0] = i1; tokW[tok*2+0] = p[i1] * inv;
        tokE[tok*2+1] = i2; tokW[tok*2+1] = p[i2] * inv;
    }
}

// ---------------- sort: single-block counting sort, no atomics ----------------
template<int ALIGN>
__global__ __launch_bounds__(SORT_T) void sort_kernel(
    const int* __restrict__ tokE, const float* __restrict__ tokW,
    int* __restrict__ aoff, int* __restrict__ tok_of_slot, float* __restrict__ w_of_slot)
{
    __shared__ int hist[NEXP * SORT_T];
    __shared__ int tot[NEXP];
    __shared__ int aoff_l[NEXP + 1];

    const int tid = threadIdx.x;
    const int lane = tid & 63, wv = tid >> 6;

    int eloc[PPT];
#pragma unroll
    for (int i = 0; i < PPT; i++) eloc[i] = tokE[tid * PPT + i];

#pragma unroll
    for (int e = 0; e < NEXP; e++) hist[e * SORT_T + tid] = 0;
    __syncthreads();
#pragma unroll
    for (int i = 0; i < PPT; i++) hist[eloc[i] * SORT_T + tid]++;
    __syncthreads();

#pragma unroll
    for (int r = 0; r < 4; r++) {
        const int e = wv * 4 + r;
        const int base = e * SORT_T + lane * 4;
        int v0 = hist[base+0], v1 = hist[base+1], v2 = hist[base+2], v3 = hist[base+3];
        const int s = v0 + v1 + v2 + v3;
        int incl = s;
#pragma unroll
        for (int off = 1; off < 64; off <<= 1) {
            const int t = __shfl_up(incl, off, 64);
            if (lane >= off) incl += t;
        }
        int run = incl - s;
        hist[base+0] = run; run += v0;
        hist[base+1] = run; run += v1;
        hist[base+2] = run; run += v2;
        hist[base+3] = run;
        if (lane == 63) tot[e] = incl;
    }
    __syncthreads();

    if (tid == 0) {
        int acc = 0;
#pragma unroll
        for (int e = 0; e < NEXP; e++) {
            aoff_l[e] = acc; aoff[e] = acc;
            acc += ((tot[e] + ALIGN - 1) / ALIGN) * ALIGN;
        }
        aoff_l[NEXP] = acc; aoff[NEXP] = acc;
    }
    __syncthreads();

#pragma unroll
    for (int i = 0; i < PPT; i++) {
        const int p = tid * PPT + i;
        const int e = eloc[i];
        const int idx = hist[e * SORT_T + tid]++;
        const int slot = aoff_l[e] + idx;
        tok_of_slot[slot] = p >> 1;
        w_of_slot[slot] = tokW[p];
    }
}

// ---------------- fc1 big: h = silu(X W1^T), 256x256, 8 waves, all-bf16 GLDS ---------
__global__ __launch_bounds__(512) void fc1_big_kernel(
    const short* __restrict__ xbf, const short* __restrict__ w1bf,
    const int* __restrict__ aoff, const int* __restrict__ tok_of_slot,
    short* __restrict__ h)
{
    const int wg = xcd_swz(blockIdx.x, NC1B * MAXRB2);
    const int colb = wg % NC1B, rowb = wg / NC1B;
    const int total = aoff[NEXP];
    const int row0 = rowb * BM2;
    if (row0 >= total) return;
    int e = 0;
    while (aoff[e+1] <= row0) e++;
    const int col0 = colb * BN2;

    __shared__ short As[BM2*BK];   // [256][32] = 16KB
    __shared__ short Bs[BN2*BK];

    const int tid = threadIdx.x, wid = tid>>6, lane = tid&63;
    const int wr = wid>>2, wc = wid&3;          // 2M x 4N wave grid
    const int srow = tid>>2;                     // 0..127 (chunk1 = +128)
    const int skc  = (tid&3)*8;

    int t0 = tok_of_slot[row0 + srow];       if (t0 < 0) t0 = 0;
    int t1 = tok_of_slot[row0 + srow + 128]; if (t1 < 0) t1 = 0;

    const short* sa0 = xbf + (size_t)t0 * H_DIM + skc;
    const short* sa1 = xbf + (size_t)t1 * H_DIM + skc;
    const short* wb  = w1bf + (size_t)e * I_DIM * H_DIM;
    const short* sb0 = wb + (size_t)(col0 + srow)       * H_DIM + skc;
    const short* sb1 = wb + (size_t)(col0 + srow + 128) * H_DIM + skc;

    short* la0 = &As[wid*512];
    short* la1 = &As[4096 + wid*512];
    short* lb0 = &Bs[wid*512];
    short* lb1 = &Bs[4096 + wid*512];

    const int frow = lane & 15, fko = (lane>>4)*8;

    f32x4 acc[8][4];
#pragma unroll
    for (int m=0;m<8;m++)
#pragma unroll
        for (int n=0;n<4;n++) acc[m][n] = (f32x4){0.f,0.f,0.f,0.f};

    for (int k0 = 0; k0 < H_DIM; k0 += BK) {
        GLDS16(sa0 + k0, la0);
        GLDS16(sa1 + k0, la1);
        GLDS16(sb0 + k0, lb0);
        GLDS16(sb1 + k0, lb1);
        __syncthreads();

        short8 bfr[4];
#pragma unroll
        for (int n=0;n<4;n++) bfr[n] = *(const short8*)&Bs[(wc*64 + n*16 + frow)*32 + fko];
#pragma unroll
        for (int m=0;m<8;m++) {
            const short8 af = *(const short8*)&As[(wr*128 + m*16 + frow)*32 + fko];
#pragma unroll
            for (int n=0;n<4;n++)
                acc[m][n] = __builtin_amdgcn_mfma_f32_16x16x32_bf16(af, bfr[n], acc[m][n], 0, 0, 0);
        }
        __syncthreads();
    }

    // epilogue: SiLU -> bf16 h. D layout: col=lane&15, row=(lane>>4)*4+r
    const int mr0 = row0 + wr*128 + (lane>>4)*4;
    const int nc0 = col0 + wc*64 + (lane&15);
#pragma unroll
    for (int m=0;m<8;m++)
#pragma unroll
        for (int n=0;n<4;n++)
#pragma unroll
            for (int r=0;r<4;r++) {
                const float v = acc[m][n][r];
                const float sv = v / (1.f + __expf(-v));
                h[(size_t)(mr0 + m*16 + r) * I_DIM + nc0 + n*16] = f2bf(sv);
            }
}

// ---------------- fc2 big: y[tok] += w * (h W2^T), 256x256, 8 waves ------------------
__global__ __launch_bounds__(512) void fc2_big_kernel(
    const short* __restrict__ h, const short* __restrict__ w2bf,
    const int* __restrict__ aoff, const int* __restrict__ tok_of_slot,
    const float* __restrict__ w_of_slot, float* __restrict__ y)
{
    const int wg = xcd_swz(blockIdx.x, NC2B * MAXRB2);
    const int colb = wg % NC2B, rowb = wg / NC2B;
    const int total = aoff[NEXP];
    const int row0 = rowb * BM2;
    if (row0 >= total) return;
    int e = 0;
    while (aoff[e+1] <= row0) e++;
    const int col0 = colb * BN2;

    __shared__ short As[BM2*BK];
    __shared__ short Bs[BN2*BK];

    const int tid = threadIdx.x, wid = tid>>6, lane = tid&63;
    const int wr = wid>>2, wc = wid&3;
    const int srow = tid>>2;
    const int skc  = (tid&3)*8;

    const short* sa0 = h + (size_t)(row0 + srow)       * I_DIM + skc;
    const short* sa1 = h + (size_t)(row0 + srow + 128) * I_DIM + skc;
    const short* wb  = w2bf + (size_t)e * H_DIM * I_DIM;
    const short* sb0 = wb + (size_t)(col0 + srow)       * I_DIM + skc;
    const short* sb1 = wb + (size_t)(col0 + srow + 128) * I_DIM + skc;

    short* la0 = &As[wid*512];
    short* la1 = &As[4096 + wid*512];
    short* lb0 = &Bs[wid*512];
    short* lb1 = &Bs[4096 + wid*512];

    const int frow = lane & 15, fko = (lane>>4)*8;

    f32x4 acc[8][4];
#pragma unroll
    for (int m=0;m<8;m++)
#pragma unroll
        for (int n=0;n<4;n++) acc[m][n] = (f32x4){0.f,0.f,0.f,0.f};

    for (int k0 = 0; k0 < I_DIM; k0 += BK) {
        GLDS16(sa0 + k0, la0);
        GLDS16(sa1 + k0, la1);
        GLDS16(sb0 + k0, lb0);
        GLDS16(sb1 + k0, lb1);
        __syncthreads();

        short8 bfr[4];
#pragma unroll
        for (int n=0;n<4;n++) bfr[n] = *(const short8*)&Bs[(wc*64 + n*16 + frow)*32 + fko];
#pragma unroll
        for (int m=0;m<8;m++) {
            const short8 af = *(const short8*)&As[(wr*128 + m*16 + frow)*32 + fko];
#pragma unroll
            for (int n=0;n<4;n++)
                acc[m][n] = __builtin_amdgcn_mfma_f32_16x16x32_bf16(af, bfr[n], acc[m][n], 0, 0, 0);
        }
        __syncthreads();
    }

    const int mr0 = row0 + wr*128 + (lane>>4)*4;
    const int nc0 = col0 + wc*64 + (lane&15);
#pragma unroll
    for (int m=0;m<8;m++)
#pragma unroll
        for (int r=0;r<4;r++) {
            const int slot = mr0 + m*16 + r;
            const int tok = tok_of_slot[slot];
            if (tok < 0) continue;
            const float w = w_of_slot[slot];
#pragma unroll
            for (int n=0;n<4;n++)
                atomicAdd(&y[(size_t)tok * H_DIM + nc0 + n*16], w * acc[m][n][r]);
        }
}

// ---------------- fc1 fallback: 128x128 dbuf, fp32 W1 reg-staged ----------------------
template<int AMODE>
__global__ __launch_bounds__(256) void fc1_kernel_t(
    const void* __restrict__ xsrc, const float* __restrict__ W1,
    const int* __restrict__ aoff, const int* __restrict__ tok_of_slot,
    short* __restrict__ h)
{
    const int wg = xcd_swz(blockIdx.x, NC1 * MAXRB1);
    const int colb = wg % NC1, rowb = wg / NC1;
    const int total = aoff[NEXP];
    const int row0 = rowb * BM;
    if (row0 >= total) return;
    int e = 0;
    while (aoff[e+1] <= row0) e++;
    const int col0 = colb * BN;

    __shared__ short As[2*ABUF];
    __shared__ short Bs[2*BBUF];

    const int tid = threadIdx.x, wid = tid>>6, lane = tid&63;
    const int wr = wid>>1, wc = wid&1;
    const int srow = wid*32 + (lane>>2);
    const int skc  = (lane&3)*8;

    int t0 = tok_of_slot[row0 + srow];      if (t0 < 0) t0 = 0;
    int t1 = tok_of_slot[row0 + srow + 16]; if (t1 < 0) t1 = 0;

    const float* wf0 = W1 + (size_t)e * I_DIM * H_DIM + (size_t)(col0 + srow)      * H_DIM + skc;
    const float* wf1 = W1 + (size_t)e * I_DIM * H_DIM + (size_t)(col0 + srow + 16) * H_DIM + skc;

    const short *sa0=nullptr,*sa1=nullptr;
    const float *fa0=nullptr,*fa1=nullptr;
    if constexpr (AMODE == 0) {
        const short* xb = (const short*)xsrc;
        sa0 = xb + (size_t)t0 * H_DIM + skc;
        sa1 = xb + (size_t)t1 * H_DIM + skc;
    } else {
        const float* xf = (const float*)xsrc;
        fa0 = xf + (size_t)t0 * H_DIM + skc;
        fa1 = xf + (size_t)t1 * H_DIM + skc;
    }
    short* la0 = &As[(wid*2+0)*512];
    short* la1 = &As[(wid*2+1)*512];

    const int frow = lane & 15, fko = (lane>>4)*8;

    f32x4 acc[4][4];
#pragma unroll
    for (int m=0;m<4;m++)
#pragma unroll
        for (int n=0;n<4;n++) acc[m][n] = (f32x4){0.f,0.f,0.f,0.f};

    float4 b00 = *(const float4*)(wf0), b01 = *(const float4*)(wf0+4);
    float4 b10 = *(const float4*)(wf1), b11 = *(const float4*)(wf1+4);
    float4 a00, a01, a10, a11;
    if constexpr (AMODE == 0) {
        GLDS16(sa0, la0);
        GLDS16(sa1, la1);
    } else {
        a00 = *(const float4*)(fa0); a01 = *(const float4*)(fa0+4);
        a10 = *(const float4*)(fa1); a11 = *(const float4*)(fa1+4);
        *(short8*)&As[srow*32 + skc]      = pack8(a00, a01);
        *(short8*)&As[(srow+16)*32 + skc] = pack8(a10, a11);
    }
    *(short8*)&Bs[srow*32 + skc]      = pack8(b00, b01);
    *(short8*)&Bs[(srow+16)*32 + skc] = pack8(b10, b11);
    __syncthreads();

    const int NT = H_DIM / BK;
    int cur = 0;
    for (int t = 0; t < NT; ++t) {
        const int kn = (t+1)*BK;
        const bool more = (t+1 < NT);
        if (more) {
            if constexpr (AMODE == 0) {
                GLDS16(sa0 + kn, la0 + (cur^1)*ABUF);
                GLDS16(sa1 + kn, la1 + (cur^1)*ABUF);
            } else {
                a00 = *(const float4*)(fa0+kn); a01 = *(const float4*)(fa0+kn+4);
                a10 = *(const float4*)(fa1+kn); a11 = *(const float4*)(fa1+kn+4);
            }
            b00 = *(const float4*)(wf0+kn); b01 = *(const float4*)(wf0+kn+4);
            b10 = *(const float4*)(wf1+kn); b11 = *(const float4*)(wf1+kn+4);
        }

        short8 af[4], bfr[4];
#pragma unroll
        for (int m=0;m<4;m++) af[m]  = *(const short8*)&As[cur*ABUF + (wr*64 + m*16 + frow)*32 + fko];
#pragma unroll
        for (int n=0;n<4;n++) bfr[n] = *(const short8*)&Bs[cur*BBUF + (wc*64 + n*16 + frow)*32 + fko];
#pragma unroll
        for (int m=0;m<4;m++)
#pragma unroll
            for (int n=0;n<4;n++)
                acc[m][n] = __builtin_amdgcn_mfma_f32_16x16x32_bf16(af[m], bfr[n], acc[m][n], 0, 0, 0);

        if (more) {
            if constexpr (AMODE == 1) {
                *(short8*)&As[(cur^1)*ABUF + srow*32 + skc]      = pack8(a00, a01);
                *(short8*)&As[(cur^1)*ABUF + (srow+16)*32 + skc] = pack8(a10, a11);
            }
            *(short8*)&Bs[(cur^1)*BBUF + srow*32 + skc]      = pack8(b00, b01);
            *(short8*)&Bs[(cur^1)*BBUF + (srow+16)*32 + skc] = pack8(b10, b11);
        }
        __syncthreads();
        cur ^= 1;
    }

    const int mr0 = row0 + wr*64 + (lane>>4)*4;
    const int nc0 = col0 + wc*64 + (lane&15);
#pragma unroll
    for (int m=0;m<4;m++)
#pragma unroll
        for (int n=0;n<4;n++)
#pragma unroll
            for (int r=0;r<4;r++) {
                const float v = acc[m][n][r];
                const float sv = v / (1.f + __expf(-v));
                h[(size_t)(mr0 + m*16 + r) * I_DIM + nc0 + n*16] = f2bf(sv);
            }
}

// ---------------- fc2 fallback: 128x128 single-buffer, fp32 W2 reg-staged -------------
__global__ __launch_bounds__(256) void fc2_kernel_f(
    const short* __restrict__ h, const float* __restrict__ W2,
    const int* __restrict__ aoff, const int* __restrict__ tok_of_slot,
    const float* __restrict__ w_of_slot, float* __restrict__ y)
{
    const int wg = xcd_swz(blockIdx.x, NC2 * MAXRB1);
    const int colb = wg % NC2, rowb = wg / NC2;
    const int total = aoff[NEXP];
    const int row0 = rowb * BM;
    if (row0 >= total) return;
    int e = 0;
    while (aoff[e+1] <= row0) e++;
    const int col0 = colb * BN;

    __shared__ short As[ABUF];
    __shared__ short Bs[BBUF];

    const int tid = threadIdx.x, wid = tid>>6, lane = tid&63;
    const int wr = wid>>1, wc = wid&1;
    const int srow = wid*32 + (lane>>2);
    const int skc  = (lane&3)*8;

    const short* sa0 = h + (size_t)(row0 + srow)      * I_DIM + skc;
    const short* sa1 = h + (size_t)(row0 + srow + 16) * I_DIM + skc;
    const float* fb0 = W2 + (size_t)e * H_DIM * I_DIM + (size_t)(col0 + srow)      * I_DIM + skc;
    const float* fb1 = W2 + (size_t)e * H_DIM * I_DIM + (size_t)(col0 + srow + 16) * I_DIM + skc;

    short* la0 = &As[(wid*2+0)*512];
    short* la1 = &As[(wid*2+1)*512];

    const int frow = lane & 15, fko = (lane>>4)*8;

    f32x4 acc[4][4];
#pragma unroll
    for (int m=0;m<4;m++)
#pragma unroll
        for (int n=0;n<4;n++) acc[m][n] = (f32x4){0.f,0.f,0.f,0.f};

    for (int k0 = 0; k0 < I_DIM; k0 += BK) {
        GLDS16(sa0 + k0, la0);
        GLDS16(sa1 + k0, la1);
        const float4 b00 = *(const float4*)(fb0 + k0), b01 = *(const float4*)(fb0 + k0 + 4);
        const float4 b10 = *(const float4*)(fb1 + k0), b11 = *(const float4*)(fb1 + k0 + 4);
        *(short8*)&Bs[srow*32 + skc]      = pack8(b00, b01);
        *(short8*)&Bs[(srow+16)*32 + skc] = pack8(b10, b11);
        __syncthreads();

        short8 af[4], bfr[4];
#pragma unroll
        for (int m=0;m<4;m++) af[m]  = *(const short8*)&As[(wr*64 + m*16 + frow)*32 + fko];
#pragma unroll
        for (int n=0;n<4;n++) bfr[n] = *(const short8*)&Bs[(wc*64 + n*16 + frow)*32 + fko];
#pragma unroll
        for (int m=0;m<4;m++)
#pragma unroll
            for (int n=0;n<4;n++)
                acc[m][n] = __builtin_amdgcn_mfma_f32_16x16x32_bf16(af[m], bfr[n], acc[m][n], 0, 0, 0);
        __syncthreads();
    }

    const int mr0 = row0 + wr*64 + (lane>>4)*4;
    const int nc0 = col0 + wc*64 + (lane&15);
#pragma unroll
    for (int m=0;m<4;m++)
#pragma unroll
        for (int r=0;r<4;r++) {
            const int slot = mr0 + m*16 + r;
            const int tok = tok_of_slot[slot];
            if (tok < 0) continue;
            const float w = w_of_slot[slot];
#pragma unroll
            for (int n=0;n<4;n++)
                atomicAdd(&y[(size_t)tok * H_DIM + nc0 + n*16], w * acc[m][n][r]);
        }
}

// ---------------- launch ----------------
extern "C" void kernel_launch(void* const* d_in, const int* in_sizes, int n_in,
                              void* d_out, int out_size, void* d_ws, size_t ws_size,
                              hipStream_t stream) {
    const float* x  = (const float*)d_in[0];
    const float* Wg = (const float*)d_in[1];
    const float* W1 = (const float*)d_in[2];
    const float* W2 = (const float*)d_in[3];
    float* y = (float*)d_out;

    char* ws = (char*)d_ws;
    int*   aoff        = (int*)  (ws + 128);
    int*   tokE        = (int*)  (ws + OFF_TOKE);
    float* tokW        = (float*)(ws + OFF_TOKW);
    int*   tok_of_slot = (int*)  (ws + OFF_TOS);
    float* w_of_slot   = (float*)(ws + OFF_WOS);
    short* h           = (short*)(ws + OFF_H);
    short* xbf         = (short*)(ws + OFF_XBF);
    short* wbf         = (short*)(ws + OFF_WBF);

    const bool full   = (ws_size >= NEED_FULL);
    const bool hasXbf = (ws_size >= NEED_XBF);

    hipMemsetAsync(tok_of_slot, 0xFF, MAXS*4, stream);
    hipMemsetAsync(y, 0, (size_t)out_size * 4, stream);

    if (full) {
        gate_kernel<true><<<NTOK/4, 256, 0, stream>>>(x, Wg, tokE, tokW, xbf);
        sort_kernel<BM2><<<1, SORT_T, 0, stream>>>(tokE, tokW, aoff, tok_of_slot, w_of_slot);
        conv_kernel<<<2048, 256, 0, stream>>>(W1, wbf, NEXP*I_DIM*H_DIM/8);
        fc1_big_kernel<<<NC1B*MAXRB2, 512, 0, stream>>>(xbf, wbf, aoff, tok_of_slot, h);
        conv_kernel<<<2048, 256, 0, stream>>>(W2, wbf, NEXP*H_DIM*I_DIM/8);
        fc2_big_kernel<<<NC2B*MAXRB2, 512, 0, stream>>>(h, wbf, aoff, tok_of_slot, w_of_slot, y);
    } else if (hasXbf) {
        gate_kernel<true><<<NTOK/4, 256, 0, stream>>>(x, Wg, tokE, tokW, xbf);
        sort_kernel<BM><<<1, SORT_T, 0, stream>>>(tokE, tokW, aoff, tok_of_slot, w_of_slot);
        fc1_kernel_t<0><<<NC1*MAXRB1, 256, 0, stream>>>(xbf, W1, aoff, tok_of_slot, h);
        fc2_kernel_f<<<NC2*MAXRB1, 256, 0, stream>>>(h, W2, aoff, tok_of_slot, w_of_slot, y);
    } else {
        gate_kernel<false><<<NTOK/4, 256, 0, stream>>>(x, Wg, tokE, tokW, nullptr);
        sort_kernel<BM><<<1, SORT_T, 0, stream>>>(tokE, tokW, aoff, tok_of_slot, w_of_slot);
        fc1_kernel_t<1><<<NC1*MAXRB1, 256, 0, stream>>>(x, W1, aoff, tok_of_slot, h);
        fc2_kernel_f<<<NC2*MAXRB1, 256, 0, stream>>>(h, W2, aoff, tok_of_slot, w_of_slot, y);
    }
}

// Round 18
// 270.828 us; speedup vs baseline: 1.2067x; 1.2067x over previous
//
#include <hip/hip_runtime.h>
#include <hip/hip_bf16.h>

#define H_DIM 1024
#define I_DIM 2048
#define NEXP  16
#define NTOK  4096
#define BM 128
#define BN 128
#define BK 32
#define ABUF (BM*BK)                 // shorts per A buffer
#define BBUF (BN*BK)
#define MAXS 10240
#define MAXRB (MAXS/BM)              // 80 row blocks
#define NC1 (I_DIM/BN)               // 16 col blocks (fc1)
#define NC2 (H_DIM/BN)               // 8  col blocks (fc2)
#define PAIRS (NTOK*2)
#define SORT_T 256
#define PPT (PAIRS/SORT_T)
#define CVB 1024                     // conv blocks per weight in merged conv

typedef __attribute__((ext_vector_type(8))) short short8;
typedef __attribute__((ext_vector_type(4))) short short4v;
typedef __attribute__((ext_vector_type(4))) float f32x4;

// ws layout (bytes)
#define OFF_TOKE 256
#define OFF_TOKW (OFF_TOKE + PAIRS*4)
#define OFF_TOS  (OFF_TOKW + PAIRS*4)
#define OFF_WOS  (OFF_TOS + MAXS*4)
#define OFF_H    (OFF_WOS + MAXS*4)
#define OFF_XBF  (OFF_H + (size_t)MAXS*I_DIM*2)              // 42090752
#define OFF_WBF  (OFF_XBF + (size_t)NTOK*H_DIM*2)            // 50479360
#define OFF_W2BF (OFF_WBF + (size_t)NEXP*I_DIM*H_DIM*2)      // 117588224
#define NEED_XBF OFF_WBF
#define NEED_FULL OFF_W2BF                                    // one weight buffer
#define NEED_A   (OFF_W2BF + (size_t)NEXP*I_DIM*H_DIM*2)      // 184697088, two buffers

#define GLDS16(gsrc, ldst) \
  __builtin_amdgcn_global_load_lds((const __attribute__((address_space(1))) void*)(gsrc), \
                                   (__attribute__((address_space(3))) void*)(ldst), 16, 0, 0)

__device__ inline short f2bf(float f) {
    union { float f; unsigned u; } v; v.f = f;
    unsigned u = v.u + 0x7FFFu + ((v.u >> 16) & 1u);   // RNE
    return (short)(u >> 16);
}

__device__ inline short8 pack8(const float4 a, const float4 b) {
    return (short8){ f2bf(a.x), f2bf(a.y), f2bf(a.z), f2bf(a.w),
                     f2bf(b.x), f2bf(b.y), f2bf(b.z), f2bf(b.w) };
}

__device__ inline int xcd_swz(int bid, int nwg) {
    return (bid & 7) * (nwg >> 3) + (bid >> 3);
}

// ---------------- fp32 -> bf16 streaming convert ----------------
__device__ inline void conv_body(const float* __restrict__ src, short* __restrict__ dst,
                                 int n8, int bid, int nb)
{
    int i = bid * 256 + threadIdx.x;
    const int stride = nb * 256;
    for (; i < n8; i += stride) {
        const float4 f0 = ((const float4*)src)[2*i];
        const float4 f1 = ((const float4*)src)[2*i+1];
        ((short8*)dst)[i] = pack8(f0, f1);
    }
}

__global__ __launch_bounds__(256) void conv_kernel(
    const float* __restrict__ src, short* __restrict__ dst, int n8)
{
    conv_body(src, dst, n8, blockIdx.x, gridDim.x);
}

// merged: blocks [0,CVB) convert W1, [CVB,2*CVB) convert W2 (identical bodies)
__global__ __launch_bounds__(256) void convW_kernel(
    const float* __restrict__ W1, short* __restrict__ w1bf,
    const float* __restrict__ W2, short* __restrict__ w2bf)
{
    const int b = blockIdx.x;
    if (b < CVB) conv_body(W1, w1bf, NEXP*I_DIM*H_DIM/8, b, CVB);
    else         conv_body(W2, w2bf, NEXP*H_DIM*I_DIM/8, b - CVB, CVB);
}

// ---------------- gate: 2 waves per token (halved latency chain) ----------------------
template<bool WRITE_XBF>
__global__ __launch_bounds__(256) void gate_kernel(
    const float* __restrict__ x, const float* __restrict__ Wg,
    int* __restrict__ tokE, float* __restrict__ tokW, short* __restrict__ xbf)
{
    __shared__ float part[2][2][NEXP];

    const int tl   = threadIdx.x >> 7;          // token within block (0..1)
    const int half = (threadIdx.x >> 6) & 1;    // H half handled by this wave
    const int lane = threadIdx.x & 63;
    const int tok  = blockIdx.x * 2 + tl;
    const float4* xr = (const float4*)(x + (size_t)tok * H_DIM);
    const int j0 = half * (H_DIM/8);            // float4 offset of this half

    float acc[NEXP];
#pragma unroll
    for (int e = 0; e < NEXP; e++) acc[e] = 0.f;
#pragma unroll
    for (int j = 0; j < H_DIM/8; j += 64) {     // 2 iterations
        const float4 xv = xr[j0 + j + lane];
        if constexpr (WRITE_XBF) {
            *(short4v*)(xbf + (size_t)tok * H_DIM + (j0 + j + lane) * 4) =
                (short4v){ f2bf(xv.x), f2bf(xv.y), f2bf(xv.z), f2bf(xv.w) };
        }
#pragma unroll
        for (int e = 0; e < NEXP; e++) {
            const float4 wv = ((const float4*)(Wg + e * H_DIM))[j0 + j + lane];
            acc[e] = fmaf(xv.x, wv.x, fmaf(xv.y, wv.y, fmaf(xv.z, wv.z, fmaf(xv.w, wv.w, acc[e]))));
        }
    }
#pragma unroll
    for (int off = 32; off; off >>= 1) {
#pragma unroll
        for (int e = 0; e < NEXP; e++) acc[e] += __shfl_xor(acc[e], off, 64);
    }
    if (lane == 0) {
#pragma unroll
        for (int e = 0; e < NEXP; e++) part[tl][half][e] = acc[e];
    }
    __syncthreads();

    if (threadIdx.x < 2) {
        const int t = threadIdx.x;
        float lg[NEXP];
#pragma unroll
        for (int e = 0; e < NEXP; e++) lg[e] = part[t][0][e] + part[t][1][e];
        float m = lg[0];
#pragma unroll
        for (int e = 1; e < NEXP; e++) m = fmaxf(m, lg[e]);
        float p[NEXP]; float s = 0.f;
#pragma unroll
        for (int e = 0; e < NEXP; e++) { p[e] = __expf(lg[e] - m); s += p[e]; }
        int i1 = 0;
#pragma unroll
        for (int e = 1; e < NEXP; e++) if (lg[e] > lg[i1]) i1 = e;
        int i2 = -1;
#pragma unroll
        for (int e = 0; e < NEXP; e++) {
            if (e == i1) continue;
            if (i2 < 0 || lg[e] > lg[i2]) i2 = e;
        }
        const int gt = blockIdx.x * 2 + t;
        const float inv = 1.f / s;
        tokE[gt*2+0] = i1; tokW[gt*2+0] = p[i1] * inv;
        tokE[gt*2+1] = i2; tokW[gt*2+1] = p[i2] * inv;
    }
}

// ---------------- sort: single-block counting sort, no atomics ----------------
__global__ __launch_bounds__(SORT_T) void sort_kernel(
    const int* __restrict__ tokE, const float* __restrict__ tokW,
    int* __restrict__ aoff, int* __restrict__ tok_of_slot, float* __restrict__ w_of_slot)
{
    __shared__ int hist[NEXP * SORT_T];
    __shared__ int tot[NEXP];
    __shared__ int aoff_l[NEXP + 1];

    const int tid = threadIdx.x;
    const int lane = tid & 63, wv = tid >> 6;

    int eloc[PPT];
#pragma unroll
    for (int i = 0; i < PPT; i++) eloc[i] = tokE[tid * PPT + i];

#pragma unroll
    for (int e = 0; e < NEXP; e++) hist[e * SORT_T + tid] = 0;
    __syncthreads();
#pragma unroll
    for (int i = 0; i < PPT; i++) hist[eloc[i] * SORT_T + tid]++;
    __syncthreads();

#pragma unroll
    for (int r = 0; r < 4; r++) {
        const int e = wv * 4 + r;
        const int base = e * SORT_T + lane * 4;
        int v0 = hist[base+0], v1 = hist[base+1], v2 = hist[base+2], v3 = hist[base+3];
        const int s = v0 + v1 + v2 + v3;
        int incl = s;
#pragma unroll
        for (int off = 1; off < 64; off <<= 1) {
            const int t = __shfl_up(incl, off, 64);
            if (lane >= off) incl += t;
        }
        int run = incl - s;
        hist[base+0] = run; run += v0;
        hist[base+1] = run; run += v1;
        hist[base+2] = run; run += v2;
        hist[base+3] = run;
        if (lane == 63) tot[e] = incl;
    }
    __syncthreads();

    if (tid == 0) {
        int acc = 0;
#pragma unroll
        for (int e = 0; e < NEXP; e++) {
            aoff_l[e] = acc; aoff[e] = acc;
            acc += ((tot[e] + BM - 1) / BM) * BM;
        }
        aoff_l[NEXP] = acc; aoff[NEXP] = acc;
    }
    __syncthreads();

#pragma unroll
    for (int i = 0; i < PPT; i++) {
        const int p = tid * PPT + i;
        const int e = eloc[i];
        const int idx = hist[e * SORT_T + tid]++;
        const int slot = aoff_l[e] + idx;
        tok_of_slot[slot] = p >> 1;
        w_of_slot[slot] = tokW[p];
    }
}

// ---------------- fc1 (full path): h = silu(X W1^T), all-bf16 GLDS, single buffer ----
__global__ __launch_bounds__(256) void fc1_bf16_kernel(
    const short* __restrict__ xbf, const short* __restrict__ w1bf,
    const int* __restrict__ aoff, const int* __restrict__ tok_of_slot,
    short* __restrict__ h)
{
    const int wg = xcd_swz(blockIdx.x, NC1 * MAXRB);
    const int colb = wg % NC1, rowb = wg / NC1;
    const int total = aoff[NEXP];
    const int row0 = rowb * BM;
    if (row0 >= total) return;
    int e = 0;
    while (aoff[e+1] <= row0) e++;
    const int col0 = colb * BN;

    __shared__ short As[ABUF];
    __shared__ short Bs[BBUF];

    const int tid = threadIdx.x, wid = tid>>6, lane = tid&63;
    const int wr = wid>>1, wc = wid&1;
    const int srow = wid*32 + (lane>>2);
    const int skc  = (lane&3)*8;

    int t0 = tok_of_slot[row0 + srow];      if (t0 < 0) t0 = 0;
    int t1 = tok_of_slot[row0 + srow + 16]; if (t1 < 0) t1 = 0;

    const short* sa0 = xbf + (size_t)t0 * H_DIM + skc;
    const short* sa1 = xbf + (size_t)t1 * H_DIM + skc;
    const short* wb  = w1bf + (size_t)e * I_DIM * H_DIM;
    const short* sb0 = wb + (size_t)(col0 + srow)      * H_DIM + skc;
    const short* sb1 = wb + (size_t)(col0 + srow + 16) * H_DIM + skc;

    short* la0 = &As[(wid*2+0)*512];
    short* la1 = &As[(wid*2+1)*512];
    short* lb0 = &Bs[(wid*2+0)*512];
    short* lb1 = &Bs[(wid*2+1)*512];

    const int frow = lane & 15, fko = (lane>>4)*8;

    f32x4 acc[4][4];
#pragma unroll
    for (int m=0;m<4;m++)
#pragma unroll
        for (int n=0;n<4;n++) acc[m][n] = (f32x4){0.f,0.f,0.f,0.f};

    for (int k0 = 0; k0 < H_DIM; k0 += BK) {
        GLDS16(sa0 + k0, la0);
        GLDS16(sa1 + k0, la1);
        GLDS16(sb0 + k0, lb0);
        GLDS16(sb1 + k0, lb1);
        __syncthreads();

        short8 af[4], bfr[4];
#pragma unroll
        for (int m=0;m<4;m++) af[m]  = *(const short8*)&As[(wr*64 + m*16 + frow)*32 + fko];
#pragma unroll
        for (int n=0;n<4;n++) bfr[n] = *(const short8*)&Bs[(wc*64 + n*16 + frow)*32 + fko];
#pragma unroll
        for (int m=0;m<4;m++)
#pragma unroll
            for (int n=0;n<4;n++)
                acc[m][n] = __builtin_amdgcn_mfma_f32_16x16x32_bf16(af[m], bfr[n], acc[m][n], 0, 0, 0);
        __syncthreads();
    }

    // epilogue: SiLU -> bf16 h. D layout: col=lane&15, row=(lane>>4)*4+r
    const int mr0 = row0 + wr*64 + (lane>>4)*4;
    const int nc0 = col0 + wc*64 + (lane&15);
#pragma unroll
    for (int m=0;m<4;m++)
#pragma unroll
        for (int n=0;n<4;n++)
#pragma unroll
            for (int r=0;r<4;r++) {
                const float v = acc[m][n][r];
                const float sv = v / (1.f + __expf(-v));
                h[(size_t)(mr0 + m*16 + r) * I_DIM + nc0 + n*16] = f2bf(sv);
            }
}

// ---------------- fc1 fallback: 128x128 dbuf, fp32 W1 reg-staged ----------------------
template<int AMODE>
__global__ __launch_bounds__(256) void fc1_kernel_t(
    const void* __restrict__ xsrc, const float* __restrict__ W1,
    const int* __restrict__ aoff, const int* __restrict__ tok_of_slot,
    short* __restrict__ h)
{
    const int wg = xcd_swz(blockIdx.x, NC1 * MAXRB);
    const int colb = wg % NC1, rowb = wg / NC1;
    const int total = aoff[NEXP];
    const int row0 = rowb * BM;
    if (row0 >= total) return;
    int e = 0;
    while (aoff[e+1] <= row0) e++;
    const int col0 = colb * BN;

    __shared__ short As[2*ABUF];
    __shared__ short Bs[2*BBUF];

    const int tid = threadIdx.x, wid = tid>>6, lane = tid&63;
    const int wr = wid>>1, wc = wid&1;
    const int srow = wid*32 + (lane>>2);
    const int skc  = (lane&3)*8;

    int t0 = tok_of_slot[row0 + srow];      if (t0 < 0) t0 = 0;
    int t1 = tok_of_slot[row0 + srow + 16]; if (t1 < 0) t1 = 0;

    const float* wf0 = W1 + (size_t)e * I_DIM * H_DIM + (size_t)(col0 + srow)      * H_DIM + skc;
    const float* wf1 = W1 + (size_t)e * I_DIM * H_DIM + (size_t)(col0 + srow + 16) * H_DIM + skc;

    const short *sa0=nullptr,*sa1=nullptr;
    const float *fa0=nullptr,*fa1=nullptr;
    if constexpr (AMODE == 0) {
        const short* xb = (const short*)xsrc;
        sa0 = xb + (size_t)t0 * H_DIM + skc;
        sa1 = xb + (size_t)t1 * H_DIM + skc;
    } else {
        const float* xf = (const float*)xsrc;
        fa0 = xf + (size_t)t0 * H_DIM + skc;
        fa1 = xf + (size_t)t1 * H_DIM + skc;
    }
    short* la0 = &As[(wid*2+0)*512];
    short* la1 = &As[(wid*2+1)*512];

    const int frow = lane & 15, fko = (lane>>4)*8;

    f32x4 acc[4][4];
#pragma unroll
    for (int m=0;m<4;m++)
#pragma unroll
        for (int n=0;n<4;n++) acc[m][n] = (f32x4){0.f,0.f,0.f,0.f};

    float4 b00 = *(const float4*)(wf0), b01 = *(const float4*)(wf0+4);
    float4 b10 = *(const float4*)(wf1), b11 = *(const float4*)(wf1+4);
    float4 a00, a01, a10, a11;
    if constexpr (AMODE == 0) {
        GLDS16(sa0, la0);
        GLDS16(sa1, la1);
    } else {
        a00 = *(const float4*)(fa0); a01 = *(const float4*)(fa0+4);
        a10 = *(const float4*)(fa1); a11 = *(const float4*)(fa1+4);
        *(short8*)&As[srow*32 + skc]      = pack8(a00, a01);
        *(short8*)&As[(srow+16)*32 + skc] = pack8(a10, a11);
    }
    *(short8*)&Bs[srow*32 + skc]      = pack8(b00, b01);
    *(short8*)&Bs[(srow+16)*32 + skc] = pack8(b10, b11);
    __syncthreads();

    const int NT = H_DIM / BK;
    int cur = 0;
    for (int t = 0; t < NT; ++t) {
        const int kn = (t+1)*BK;
        const bool more = (t+1 < NT);
        if (more) {
            if constexpr (AMODE == 0) {
                GLDS16(sa0 + kn, la0 + (cur^1)*ABUF);
                GLDS16(sa1 + kn, la1 + (cur^1)*ABUF);
            } else {
                a00 = *(const float4*)(fa0+kn); a01 = *(const float4*)(fa0+kn+4);
                a10 = *(const float4*)(fa1+kn); a11 = *(const float4*)(fa1+kn+4);
            }
            b00 = *(const float4*)(wf0+kn); b01 = *(const float4*)(wf0+kn+4);
            b10 = *(const float4*)(wf1+kn); b11 = *(const float4*)(wf1+kn+4);
        }

        short8 af[4], bfr[4];
#pragma unroll
        for (int m=0;m<4;m++) af[m]  = *(const short8*)&As[cur*ABUF + (wr*64 + m*16 + frow)*32 + fko];
#pragma unroll
        for (int n=0;n<4;n++) bfr[n] = *(const short8*)&Bs[cur*BBUF + (wc*64 + n*16 + frow)*32 + fko];
#pragma unroll
        for (int m=0;m<4;m++)
#pragma unroll
            for (int n=0;n<4;n++)
                acc[m][n] = __builtin_amdgcn_mfma_f32_16x16x32_bf16(af[m], bfr[n], acc[m][n], 0, 0, 0);

        if (more) {
            if constexpr (AMODE == 1) {
                *(short8*)&As[(cur^1)*ABUF + srow*32 + skc]      = pack8(a00, a01);
                *(short8*)&As[(cur^1)*ABUF + (srow+16)*32 + skc] = pack8(a10, a11);
            }
            *(short8*)&Bs[(cur^1)*BBUF + srow*32 + skc]      = pack8(b00, b01);
            *(short8*)&Bs[(cur^1)*BBUF + (srow+16)*32 + skc] = pack8(b10, b11);
        }
        __syncthreads();
        cur ^= 1;
    }

    const int mr0 = row0 + wr*64 + (lane>>4)*4;
    const int nc0 = col0 + wc*64 + (lane&15);
#pragma unroll
    for (int m=0;m<4;m++)
#pragma unroll
        for (int n=0;n<4;n++)
#pragma unroll
            for (int r=0;r<4;r++) {
                const float v = acc[m][n][r];
                const float sv = v / (1.f + __expf(-v));
                h[(size_t)(mr0 + m*16 + r) * I_DIM + nc0 + n*16] = f2bf(sv);
            }
}

// ---------------- fc2: y[tok] += w * (h W2^T), 128x128 single-buffer, bf16 GLDS ------
template<int MODE>
__global__ __launch_bounds__(256) void fc2_kernel_t(
    const short* __restrict__ h, const void* __restrict__ w2src,
    const int* __restrict__ aoff, const int* __restrict__ tok_of_slot,
    const float* __restrict__ w_of_slot, float* __restrict__ y)
{
    const int wg = xcd_swz(blockIdx.x, NC2 * MAXRB);
    const int colb = wg % NC2, rowb = wg / NC2;
    const int total = aoff[NEXP];
    const int row0 = rowb * BM;
    if (row0 >= total) return;
    int e = 0;
    while (aoff[e+1] <= row0) e++;
    const int col0 = colb * BN;

    __shared__ short As[ABUF];
    __shared__ short Bs[BBUF];

    const int tid = threadIdx.x, wid = tid>>6, lane = tid&63;
    const int wr = wid>>1, wc = wid&1;
    const int srow = wid*32 + (lane>>2);
    const int skc  = (lane&3)*8;

    const short* sa0 = h + (size_t)(row0 + srow)      * I_DIM + skc;
    const short* sa1 = h + (size_t)(row0 + srow + 16) * I_DIM + skc;

    const short *sb0=nullptr,*sb1=nullptr;
    const float *fb0=nullptr,*fb1=nullptr;
    if constexpr (MODE == 0) {
        const short* wb = (const short*)w2src + (size_t)e * H_DIM * I_DIM;
        sb0 = wb + (size_t)(col0 + srow)      * I_DIM + skc;
        sb1 = wb + (size_t)(col0 + srow + 16) * I_DIM + skc;
    } else {
        const float* wf = (const float*)w2src + (size_t)e * H_DIM * I_DIM;
        fb0 = wf + (size_t)(col0 + srow)      * I_DIM + skc;
        fb1 = wf + (size_t)(col0 + srow + 16) * I_DIM + skc;
    }
    short* la0 = &As[(wid*2+0)*512];
    short* la1 = &As[(wid*2+1)*512];
    short* lb0 = &Bs[(wid*2+0)*512];
    short* lb1 = &Bs[(wid*2+1)*512];

    const int frow = lane & 15, fko = (lane>>4)*8;

    f32x4 acc[4][4];
#pragma unroll
    for (int m=0;m<4;m++)
#pragma unroll
        for (int n=0;n<4;n++) acc[m][n] = (f32x4){0.f,0.f,0.f,0.f};

    for (int k0 = 0; k0 < I_DIM; k0 += BK) {
        GLDS16(sa0 + k0, la0);
        GLDS16(sa1 + k0, la1);
        if constexpr (MODE == 0) {
            GLDS16(sb0 + k0, lb0);
            GLDS16(sb1 + k0, lb1);
        } else {
            const float4 b00 = *(const float4*)(fb0 + k0), b01 = *(const float4*)(fb0 + k0 + 4);
            const float4 b10 = *(const float4*)(fb1 + k0), b11 = *(const float4*)(fb1 + k0 + 4);
            *(short8*)&Bs[srow*32 + skc]      = pack8(b00, b01);
            *(short8*)&Bs[(srow+16)*32 + skc] = pack8(b10, b11);
        }
        __syncthreads();

        short8 af[4], bfr[4];
#pragma unroll
        for (int m=0;m<4;m++) af[m]  = *(const short8*)&As[(wr*64 + m*16 + frow)*32 + fko];
#pragma unroll
        for (int n=0;n<4;n++) bfr[n] = *(const short8*)&Bs[(wc*64 + n*16 + frow)*32 + fko];
#pragma unroll
        for (int m=0;m<4;m++)
#pragma unroll
            for (int n=0;n<4;n++)
                acc[m][n] = __builtin_amdgcn_mfma_f32_16x16x32_bf16(af[m], bfr[n], acc[m][n], 0, 0, 0);
        __syncthreads();
    }

    const int mr0 = row0 + wr*64 + (lane>>4)*4;
    const int nc0 = col0 + wc*64 + (lane&15);
#pragma unroll
    for (int m=0;m<4;m++)
#pragma unroll
        for (int r=0;r<4;r++) {
            const int slot = mr0 + m*16 + r;
            const int tok = tok_of_slot[slot];
            if (tok < 0) continue;
            const float w = w_of_slot[slot];
#pragma unroll
            for (int n=0;n<4;n++)
                atomicAdd(&y[(size_t)tok * H_DIM + nc0 + n*16], w * acc[m][n][r]);
        }
}

// ---------------- launch ----------------
extern "C" void kernel_launch(void* const* d_in, const int* in_sizes, int n_in,
                              void* d_out, int out_size, void* d_ws, size_t ws_size,
                              hipStream_t stream) {
    const float* x  = (const float*)d_in[0];
    const float* Wg = (const float*)d_in[1];
    const float* W1 = (const float*)d_in[2];
    const float* W2 = (const float*)d_in[3];
    float* y = (float*)d_out;

    char* ws = (char*)d_ws;
    int*   aoff        = (int*)  (ws + 128);
    int*   tokE        = (int*)  (ws + OFF_TOKE);
    float* tokW        = (float*)(ws + OFF_TOKW);
    int*   tok_of_slot = (int*)  (ws + OFF_TOS);
    float* w_of_slot   = (float*)(ws + OFF_WOS);
    short* h           = (short*)(ws + OFF_H);
    short* xbf         = (short*)(ws + OFF_XBF);
    short* wbf         = (short*)(ws + OFF_WBF);
    short* w2bf        = (short*)(ws + OFF_W2BF);

    const bool tierA  = (ws_size >= NEED_A);
    const bool full   = (ws_size >= NEED_FULL);
    const bool hasXbf = (ws_size >= NEED_XBF);

    hipMemsetAsync(tok_of_slot, 0xFF, MAXS*4, stream);
    hipMemsetAsync(y, 0, (size_t)out_size * 4, stream);

    if (tierA) {
        gate_kernel<true><<<NTOK/2, 256, 0, stream>>>(x, Wg, tokE, tokW, xbf);
        sort_kernel<<<1, SORT_T, 0, stream>>>(tokE, tokW, aoff, tok_of_slot, w_of_slot);
        convW_kernel<<<2*CVB, 256, 0, stream>>>(W1, wbf, W2, w2bf);
        fc1_bf16_kernel<<<NC1*MAXRB, 256, 0, stream>>>(xbf, wbf, aoff, tok_of_slot, h);
        fc2_kernel_t<0><<<NC2*MAXRB, 256, 0, stream>>>(h, w2bf, aoff, tok_of_slot, w_of_slot, y);
    } else if (full) {
        gate_kernel<true><<<NTOK/2, 256, 0, stream>>>(x, Wg, tokE, tokW, xbf);
        sort_kernel<<<1, SORT_T, 0, stream>>>(tokE, tokW, aoff, tok_of_slot, w_of_slot);
        conv_kernel<<<2048, 256, 0, stream>>>(W1, wbf, NEXP*I_DIM*H_DIM/8);
        fc1_bf16_kernel<<<NC1*MAXRB, 256, 0, stream>>>(xbf, wbf, aoff, tok_of_slot, h);
        conv_kernel<<<2048, 256, 0, stream>>>(W2, wbf, NEXP*H_DIM*I_DIM/8);
        fc2_kernel_t<0><<<NC2*MAXRB, 256, 0, stream>>>(h, wbf, aoff, tok_of_slot, w_of_slot, y);
    } else if (hasXbf) {
        gate_kernel<true><<<NTOK/2, 256, 0, stream>>>(x, Wg, tokE, tokW, xbf);
        sort_kernel<<<1, SORT_T, 0, stream>>>(tokE, tokW, aoff, tok_of_slot, w_of_slot);
        fc1_kernel_t<0><<<NC1*MAXRB, 256, 0, stream>>>(xbf, W1, aoff, tok_of_slot, h);
        fc2_kernel_t<1><<<NC2*MAXRB, 256, 0, stream>>>(h, W2, aoff, tok_of_slot, w_of_slot, y);
    } else {
        gate_kernel<false><<<NTOK/2, 256, 0, stream>>>(x, Wg, tokE, tokW, nullptr);
        sort_kernel<<<1, SORT_T, 0, stream>>>(tokE, tokW, aoff, tok_of_slot, w_of_slot);
        fc1_kernel_t<1><<<NC1*MAXRB, 256, 0, stream>>>(x, W1, aoff, tok_of_slot, h);
        fc2_kernel_t<1><<<NC2*MAXRB, 256, 0, stream>>>(h, W2, aoff, tok_of_slot, w_of_slot, y);
    }
}

// Round 19
// 251.244 us; speedup vs baseline: 1.3008x; 1.0779x over previous
//
#include <hip/hip_runtime.h>
#include <hip/hip_bf16.h>

#define H_DIM 1024
#define I_DIM 2048
#define NEXP  16
#define NTOK  4096
#define BM 128
#define BN 128
#define BK 32
#define ABUF (BM*BK)                 // shorts per A buffer
#define BBUF (BN*BK)
#define MAXS 10240
#define MAXRB (MAXS/BM)              // 80 row blocks
#define NC1 (I_DIM/BN)               // 16 col blocks (fc1)
#define NC2 (H_DIM/BN)               // 8  col blocks (fc2)
#define PAIRS (NTOK*2)
#define SORT_T 256
#define PPT (PAIRS/SORT_T)

typedef __attribute__((ext_vector_type(8))) short short8;
typedef __attribute__((ext_vector_type(4))) short short4v;
typedef __attribute__((ext_vector_type(4))) float f32x4;

// ws layout (bytes)
#define OFF_TOKE 256
#define OFF_TOKW (OFF_TOKE + PAIRS*4)
#define OFF_TOS  (OFF_TOKW + PAIRS*4)
#define OFF_WOS  (OFF_TOS + MAXS*4)
#define OFF_H    (OFF_WOS + MAXS*4)
#define OFF_XBF  (OFF_H + (size_t)MAXS*I_DIM*2)              // 42090752
#define OFF_WBF  (OFF_XBF + (size_t)NTOK*H_DIM*2)            // 50479360
#define NEED_XBF OFF_WBF
#define NEED_FULL (OFF_WBF + (size_t)NEXP*I_DIM*H_DIM*2)     // 117588224

#define GLDS16(gsrc, ldst) \
  __builtin_amdgcn_global_load_lds((const __attribute__((address_space(1))) void*)(gsrc), \
                                   (__attribute__((address_space(3))) void*)(ldst), 16, 0, 0)

__device__ inline short f2bf(float f) {
    union { float f; unsigned u; } v; v.f = f;
    unsigned u = v.u + 0x7FFFu + ((v.u >> 16) & 1u);   // RNE
    return (short)(u >> 16);
}

__device__ inline short8 pack8(const float4 a, const float4 b) {
    return (short8){ f2bf(a.x), f2bf(a.y), f2bf(a.z), f2bf(a.w),
                     f2bf(b.x), f2bf(b.y), f2bf(b.z), f2bf(b.w) };
}

__device__ inline int xcd_swz(int bid, int nwg) {
    return (bid & 7) * (nwg >> 3) + (bid >> 3);
}

// ---------------- fp32 -> bf16 streaming convert (2048 blocks, 5.7 TB/s) --------------
__global__ __launch_bounds__(256) void conv_kernel(
    const float* __restrict__ src, short* __restrict__ dst, int n8)
{
    int i = blockIdx.x * blockDim.x + threadIdx.x;
    const int stride = gridDim.x * blockDim.x;
    for (; i < n8; i += stride) {
        const float4 f0 = ((const float4*)src)[2*i];
        const float4 f1 = ((const float4*)src)[2*i+1];
        ((short8*)dst)[i] = pack8(f0, f1);
    }
}

// ---------------- gate: 2 waves per token (halved latency chain) ----------------------
template<bool WRITE_XBF>
__global__ __launch_bounds__(256) void gate_kernel(
    const float* __restrict__ x, const float* __restrict__ Wg,
    int* __restrict__ tokE, float* __restrict__ tokW, short* __restrict__ xbf)
{
    __shared__ float part[2][2][NEXP];

    const int tl   = threadIdx.x >> 7;          // token within block (0..1)
    const int half = (threadIdx.x >> 6) & 1;    // H half handled by this wave
    const int lane = threadIdx.x & 63;
    const int tok  = blockIdx.x * 2 + tl;
    const float4* xr = (const float4*)(x + (size_t)tok * H_DIM);
    const int j0 = half * (H_DIM/8);            // float4 offset of this half

    float acc[NEXP];
#pragma unroll
    for (int e = 0; e < NEXP; e++) acc[e] = 0.f;
#pragma unroll
    for (int j = 0; j < H_DIM/8; j += 64) {     // 2 iterations
        const float4 xv = xr[j0 + j + lane];
        if constexpr (WRITE_XBF) {
            *(short4v*)(xbf + (size_t)tok * H_DIM + (j0 + j + lane) * 4) =
                (short4v){ f2bf(xv.x), f2bf(xv.y), f2bf(xv.z), f2bf(xv.w) };
        }
#pragma unroll
        for (int e = 0; e < NEXP; e++) {
            const float4 wv = ((const float4*)(Wg + e * H_DIM))[j0 + j + lane];
            acc[e] = fmaf(xv.x, wv.x, fmaf(xv.y, wv.y, fmaf(xv.z, wv.z, fmaf(xv.w, wv.w, acc[e]))));
        }
    }
#pragma unroll
    for (int off = 32; off; off >>= 1) {
#pragma unroll
        for (int e = 0; e < NEXP; e++) acc[e] += __shfl_xor(acc[e], off, 64);
    }
    if (lane == 0) {
#pragma unroll
        for (int e = 0; e < NEXP; e++) part[tl][half][e] = acc[e];
    }
    __syncthreads();

    if (threadIdx.x < 2) {
        const int t = threadIdx.x;
        float lg[NEXP];
#pragma unroll
        for (int e = 0; e < NEXP; e++) lg[e] = part[t][0][e] + part[t][1][e];
        float m = lg[0];
#pragma unroll
        for (int e = 1; e < NEXP; e++) m = fmaxf(m, lg[e]);
        float p[NEXP]; float s = 0.f;
#pragma unroll
        for (int e = 0; e < NEXP; e++) { p[e] = __expf(lg[e] - m); s += p[e]; }
        int i1 = 0;
#pragma unroll
        for (int e = 1; e < NEXP; e++) if (lg[e] > lg[i1]) i1 = e;
        int i2 = -1;
#pragma unroll
        for (int e = 0; e < NEXP; e++) {
            if (e == i1) continue;
            if (i2 < 0 || lg[e] > lg[i2]) i2 = e;
        }
        const int gt = blockIdx.x * 2 + t;
        const float inv = 1.f / s;
        tokE[gt*2+0] = i1; tokW[gt*2+0] = p[i1] * inv;
        tokE[gt*2+1] = i2; tokW[gt*2+1] = p[i2] * inv;
    }
}

// ---------------- sort: single-block counting sort, no atomics ----------------
__global__ __launch_bounds__(SORT_T) void sort_kernel(
    const int* __restrict__ tokE, const float* __restrict__ tokW,
    int* __restrict__ aoff, int* __restrict__ tok_of_slot, float* __restrict__ w_of_slot)
{
    __shared__ int hist[NEXP * SORT_T];
    __shared__ int tot[NEXP];
    __shared__ int aoff_l[NEXP + 1];

    const int tid = threadIdx.x;
    const int lane = tid & 63, wv = tid >> 6;

    int eloc[PPT];
#pragma unroll
    for (int i = 0; i < PPT; i++) eloc[i] = tokE[tid * PPT + i];

#pragma unroll
    for (int e = 0; e < NEXP; e++) hist[e * SORT_T + tid] = 0;
    __syncthreads();
#pragma unroll
    for (int i = 0; i < PPT; i++) hist[eloc[i] * SORT_T + tid]++;
    __syncthreads();

#pragma unroll
    for (int r = 0; r < 4; r++) {
        const int e = wv * 4 + r;
        const int base = e * SORT_T + lane * 4;
        int v0 = hist[base+0], v1 = hist[base+1], v2 = hist[base+2], v3 = hist[base+3];
        const int s = v0 + v1 + v2 + v3;
        int incl = s;
#pragma unroll
        for (int off = 1; off < 64; off <<= 1) {
            const int t = __shfl_up(incl, off, 64);
            if (lane >= off) incl += t;
        }
        int run = incl - s;
        hist[base+0] = run; run += v0;
        hist[base+1] = run; run += v1;
        hist[base+2] = run; run += v2;
        hist[base+3] = run;
        if (lane == 63) tot[e] = incl;
    }
    __syncthreads();

    if (tid == 0) {
        int acc = 0;
#pragma unroll
        for (int e = 0; e < NEXP; e++) {
            aoff_l[e] = acc; aoff[e] = acc;
            acc += ((tot[e] + BM - 1) / BM) * BM;
        }
        aoff_l[NEXP] = acc; aoff[NEXP] = acc;
    }
    __syncthreads();

#pragma unroll
    for (int i = 0; i < PPT; i++) {
        const int p = tid * PPT + i;
        const int e = eloc[i];
        const int idx = hist[e * SORT_T + tid]++;
        const int slot = aoff_l[e] + idx;
        tok_of_slot[slot] = p >> 1;
        w_of_slot[slot] = tokW[p];
    }
}

// ---------------- fc1 (full path): h = silu(X W1^T), all-bf16 GLDS, single buffer ----
__global__ __launch_bounds__(256) void fc1_bf16_kernel(
    const short* __restrict__ xbf, const short* __restrict__ w1bf,
    const int* __restrict__ aoff, const int* __restrict__ tok_of_slot,
    short* __restrict__ h)
{
    const int wg = xcd_swz(blockIdx.x, NC1 * MAXRB);
    const int colb = wg % NC1, rowb = wg / NC1;
    const int total = aoff[NEXP];
    const int row0 = rowb * BM;
    if (row0 >= total) return;
    int e = 0;
    while (aoff[e+1] <= row0) e++;
    const int col0 = colb * BN;

    __shared__ short As[ABUF];
    __shared__ short Bs[BBUF];

    const int tid = threadIdx.x, wid = tid>>6, lane = tid&63;
    const int wr = wid>>1, wc = wid&1;
    const int srow = wid*32 + (lane>>2);
    const int skc  = (lane&3)*8;

    int t0 = tok_of_slot[row0 + srow];      if (t0 < 0) t0 = 0;
    int t1 = tok_of_slot[row0 + srow + 16]; if (t1 < 0) t1 = 0;

    const short* sa0 = xbf + (size_t)t0 * H_DIM + skc;
    const short* sa1 = xbf + (size_t)t1 * H_DIM + skc;
    const short* wb  = w1bf + (size_t)e * I_DIM * H_DIM;
    const short* sb0 = wb + (size_t)(col0 + srow)      * H_DIM + skc;
    const short* sb1 = wb + (size_t)(col0 + srow + 16) * H_DIM + skc;

    short* la0 = &As[(wid*2+0)*512];
    short* la1 = &As[(wid*2+1)*512];
    short* lb0 = &Bs[(wid*2+0)*512];
    short* lb1 = &Bs[(wid*2+1)*512];

    const int frow = lane & 15, fko = (lane>>4)*8;

    f32x4 acc[4][4];
#pragma unroll
    for (int m=0;m<4;m++)
#pragma unroll
        for (int n=0;n<4;n++) acc[m][n] = (f32x4){0.f,0.f,0.f,0.f};

    for (int k0 = 0; k0 < H_DIM; k0 += BK) {
        GLDS16(sa0 + k0, la0);
        GLDS16(sa1 + k0, la1);
        GLDS16(sb0 + k0, lb0);
        GLDS16(sb1 + k0, lb1);
        __syncthreads();

        short8 af[4], bfr[4];
#pragma unroll
        for (int m=0;m<4;m++) af[m]  = *(const short8*)&As[(wr*64 + m*16 + frow)*32 + fko];
#pragma unroll
        for (int n=0;n<4;n++) bfr[n] = *(const short8*)&Bs[(wc*64 + n*16 + frow)*32 + fko];
#pragma unroll
        for (int m=0;m<4;m++)
#pragma unroll
            for (int n=0;n<4;n++)
                acc[m][n] = __builtin_amdgcn_mfma_f32_16x16x32_bf16(af[m], bfr[n], acc[m][n], 0, 0, 0);
        __syncthreads();
    }

    // epilogue: SiLU -> bf16 h. D layout: col=lane&15, row=(lane>>4)*4+r
    const int mr0 = row0 + wr*64 + (lane>>4)*4;
    const int nc0 = col0 + wc*64 + (lane&15);
#pragma unroll
    for (int m=0;m<4;m++)
#pragma unroll
        for (int n=0;n<4;n++)
#pragma unroll
            for (int r=0;r<4;r++) {
                const float v = acc[m][n][r];
                const float sv = v / (1.f + __expf(-v));
                h[(size_t)(mr0 + m*16 + r) * I_DIM + nc0 + n*16] = f2bf(sv);
            }
}

// ---------------- fc1 fallback: 128x128 dbuf, fp32 W1 reg-staged ----------------------
template<int AMODE>
__global__ __launch_bounds__(256) void fc1_kernel_t(
    const void* __restrict__ xsrc, const float* __restrict__ W1,
    const int* __restrict__ aoff, const int* __restrict__ tok_of_slot,
    short* __restrict__ h)
{
    const int wg = xcd_swz(blockIdx.x, NC1 * MAXRB);
    const int colb = wg % NC1, rowb = wg / NC1;
    const int total = aoff[NEXP];
    const int row0 = rowb * BM;
    if (row0 >= total) return;
    int e = 0;
    while (aoff[e+1] <= row0) e++;
    const int col0 = colb * BN;

    __shared__ short As[2*ABUF];
    __shared__ short Bs[2*BBUF];

    const int tid = threadIdx.x, wid = tid>>6, lane = tid&63;
    const int wr = wid>>1, wc = wid&1;
    const int srow = wid*32 + (lane>>2);
    const int skc  = (lane&3)*8;

    int t0 = tok_of_slot[row0 + srow];      if (t0 < 0) t0 = 0;
    int t1 = tok_of_slot[row0 + srow + 16]; if (t1 < 0) t1 = 0;

    const float* wf0 = W1 + (size_t)e * I_DIM * H_DIM + (size_t)(col0 + srow)      * H_DIM + skc;
    const float* wf1 = W1 + (size_t)e * I_DIM * H_DIM + (size_t)(col0 + srow + 16) * H_DIM + skc;

    const short *sa0=nullptr,*sa1=nullptr;
    const float *fa0=nullptr,*fa1=nullptr;
    if constexpr (AMODE == 0) {
        const short* xb = (const short*)xsrc;
        sa0 = xb + (size_t)t0 * H_DIM + skc;
        sa1 = xb + (size_t)t1 * H_DIM + skc;
    } else {
        const float* xf = (const float*)xsrc;
        fa0 = xf + (size_t)t0 * H_DIM + skc;
        fa1 = xf + (size_t)t1 * H_DIM + skc;
    }
    short* la0 = &As[(wid*2+0)*512];
    short* la1 = &As[(wid*2+1)*512];

    const int frow = lane & 15, fko = (lane>>4)*8;

    f32x4 acc[4][4];
#pragma unroll
    for (int m=0;m<4;m++)
#pragma unroll
        for (int n=0;n<4;n++) acc[m][n] = (f32x4){0.f,0.f,0.f,0.f};

    float4 b00 = *(const float4*)(wf0), b01 = *(const float4*)(wf0+4);
    float4 b10 = *(const float4*)(wf1), b11 = *(const float4*)(wf1+4);
    float4 a00, a01, a10, a11;
    if constexpr (AMODE == 0) {
        GLDS16(sa0, la0);
        GLDS16(sa1, la1);
    } else {
        a00 = *(const float4*)(fa0); a01 = *(const float4*)(fa0+4);
        a10 = *(const float4*)(fa1); a11 = *(const float4*)(fa1+4);
        *(short8*)&As[srow*32 + skc]      = pack8(a00, a01);
        *(short8*)&As[(srow+16)*32 + skc] = pack8(a10, a11);
    }
    *(short8*)&Bs[srow*32 + skc]      = pack8(b00, b01);
    *(short8*)&Bs[(srow+16)*32 + skc] = pack8(b10, b11);
    __syncthreads();

    const int NT = H_DIM / BK;
    int cur = 0;
    for (int t = 0; t < NT; ++t) {
        const int kn = (t+1)*BK;
        const bool more = (t+1 < NT);
        if (more) {
            if constexpr (AMODE == 0) {
                GLDS16(sa0 + kn, la0 + (cur^1)*ABUF);
                GLDS16(sa1 + kn, la1 + (cur^1)*ABUF);
            } else {
                a00 = *(const float4*)(fa0+kn); a01 = *(const float4*)(fa0+kn+4);
                a10 = *(const float4*)(fa1+kn); a11 = *(const float4*)(fa1+kn+4);
            }
            b00 = *(const float4*)(wf0+kn); b01 = *(const float4*)(wf0+kn+4);
            b10 = *(const float4*)(wf1+kn); b11 = *(const float4*)(wf1+kn+4);
        }

        short8 af[4], bfr[4];
#pragma unroll
        for (int m=0;m<4;m++) af[m]  = *(const short8*)&As[cur*ABUF + (wr*64 + m*16 + frow)*32 + fko];
#pragma unroll
        for (int n=0;n<4;n++) bfr[n] = *(const short8*)&Bs[cur*BBUF + (wc*64 + n*16 + frow)*32 + fko];
#pragma unroll
        for (int m=0;m<4;m++)
#pragma unroll
            for (int n=0;n<4;n++)
                acc[m][n] = __builtin_amdgcn_mfma_f32_16x16x32_bf16(af[m], bfr[n], acc[m][n], 0, 0, 0);

        if (more) {
            if constexpr (AMODE == 1) {
                *(short8*)&As[(cur^1)*ABUF + srow*32 + skc]      = pack8(a00, a01);
                *(short8*)&As[(cur^1)*ABUF + (srow+16)*32 + skc] = pack8(a10, a11);
            }
            *(short8*)&Bs[(cur^1)*BBUF + srow*32 + skc]      = pack8(b00, b01);
            *(short8*)&Bs[(cur^1)*BBUF + (srow+16)*32 + skc] = pack8(b10, b11);
        }
        __syncthreads();
        cur ^= 1;
    }

    const int mr0 = row0 + wr*64 + (lane>>4)*4;
    const int nc0 = col0 + wc*64 + (lane&15);
#pragma unroll
    for (int m=0;m<4;m++)
#pragma unroll
        for (int n=0;n<4;n++)
#pragma unroll
            for (int r=0;r<4;r++) {
                const float v = acc[m][n][r];
                const float sv = v / (1.f + __expf(-v));
                h[(size_t)(mr0 + m*16 + r) * I_DIM + nc0 + n*16] = f2bf(sv);
            }
}

// ---------------- fc2: y[tok] += w * (h W2^T), 128x128 single-buffer, bf16 GLDS ------
template<int MODE>
__global__ __launch_bounds__(256) void fc2_kernel_t(
    const short* __restrict__ h, const void* __restrict__ w2src,
    const int* __restrict__ aoff, const int* __restrict__ tok_of_slot,
    const float* __restrict__ w_of_slot, float* __restrict__ y)
{
    const int wg = xcd_swz(blockIdx.x, NC2 * MAXRB);
    const int colb = wg % NC2, rowb = wg / NC2;
    const int total = aoff[NEXP];
    const int row0 = rowb * BM;
    if (row0 >= total) return;
    int e = 0;
    while (aoff[e+1] <= row0) e++;
    const int col0 = colb * BN;

    __shared__ short As[ABUF];
    __shared__ short Bs[BBUF];

    const int tid = threadIdx.x, wid = tid>>6, lane = tid&63;
    const int wr = wid>>1, wc = wid&1;
    const int srow = wid*32 + (lane>>2);
    const int skc  = (lane&3)*8;

    const short* sa0 = h + (size_t)(row0 + srow)      * I_DIM + skc;
    const short* sa1 = h + (size_t)(row0 + srow + 16) * I_DIM + skc;

    const short *sb0=nullptr,*sb1=nullptr;
    const float *fb0=nullptr,*fb1=nullptr;
    if constexpr (MODE == 0) {
        const short* wb = (const short*)w2src + (size_t)e * H_DIM * I_DIM;
        sb0 = wb + (size_t)(col0 + srow)      * I_DIM + skc;
        sb1 = wb + (size_t)(col0 + srow + 16) * I_DIM + skc;
    } else {
        const float* wf = (const float*)w2src + (size_t)e * H_DIM * I_DIM;
        fb0 = wf + (size_t)(col0 + srow)      * I_DIM + skc;
        fb1 = wf + (size_t)(col0 + srow + 16) * I_DIM + skc;
    }
    short* la0 = &As[(wid*2+0)*512];
    short* la1 = &As[(wid*2+1)*512];
    short* lb0 = &Bs[(wid*2+0)*512];
    short* lb1 = &Bs[(wid*2+1)*512];

    const int frow = lane & 15, fko = (lane>>4)*8;

    f32x4 acc[4][4];
#pragma unroll
    for (int m=0;m<4;m++)
#pragma unroll
        for (int n=0;n<4;n++) acc[m][n] = (f32x4){0.f,0.f,0.f,0.f};

    for (int k0 = 0; k0 < I_DIM; k0 += BK) {
        GLDS16(sa0 + k0, la0);
        GLDS16(sa1 + k0, la1);
        if constexpr (MODE == 0) {
            GLDS16(sb0 + k0, lb0);
            GLDS16(sb1 + k0, lb1);
        } else {
            const float4 b00 = *(const float4*)(fb0 + k0), b01 = *(const float4*)(fb0 + k0 + 4);
            const float4 b10 = *(const float4*)(fb1 + k0), b11 = *(const float4*)(fb1 + k0 + 4);
            *(short8*)&Bs[srow*32 + skc]      = pack8(b00, b01);
            *(short8*)&Bs[(srow+16)*32 + skc] = pack8(b10, b11);
        }
        __syncthreads();

        short8 af[4], bfr[4];
#pragma unroll
        for (int m=0;m<4;m++) af[m]  = *(const short8*)&As[(wr*64 + m*16 + frow)*32 + fko];
#pragma unroll
        for (int n=0;n<4;n++) bfr[n] = *(const short8*)&Bs[(wc*64 + n*16 + frow)*32 + fko];
#pragma unroll
        for (int m=0;m<4;m++)
#pragma unroll
            for (int n=0;n<4;n++)
                acc[m][n] = __builtin_amdgcn_mfma_f32_16x16x32_bf16(af[m], bfr[n], acc[m][n], 0, 0, 0);
        __syncthreads();
    }

    const int mr0 = row0 + wr*64 + (lane>>4)*4;
    const int nc0 = col0 + wc*64 + (lane&15);
#pragma unroll
    for (int m=0;m<4;m++)
#pragma unroll
        for (int r=0;r<4;r++) {
            const int slot = mr0 + m*16 + r;
            const int tok = tok_of_slot[slot];
            if (tok < 0) continue;
            const float w = w_of_slot[slot];
#pragma unroll
            for (int n=0;n<4;n++)
                atomicAdd(&y[(size_t)tok * H_DIM + nc0 + n*16], w * acc[m][n][r]);
        }
}

// ---------------- launch ----------------
extern "C" void kernel_launch(void* const* d_in, const int* in_sizes, int n_in,
                              void* d_out, int out_size, void* d_ws, size_t ws_size,
                              hipStream_t stream) {
    const float* x  = (const float*)d_in[0];
    const float* Wg = (const float*)d_in[1];
    const float* W1 = (const float*)d_in[2];
    const float* W2 = (const float*)d_in[3];
    float* y = (float*)d_out;

    char* ws = (char*)d_ws;
    int*   aoff        = (int*)  (ws + 128);
    int*   tokE        = (int*)  (ws + OFF_TOKE);
    float* tokW        = (float*)(ws + OFF_TOKW);
    int*   tok_of_slot = (int*)  (ws + OFF_TOS);
    float* w_of_slot   = (float*)(ws + OFF_WOS);
    short* h           = (short*)(ws + OFF_H);
    short* xbf         = (short*)(ws + OFF_XBF);
    short* wbf         = (short*)(ws + OFF_WBF);

    const bool full   = (ws_size >= NEED_FULL);
    const bool hasXbf = (ws_size >= NEED_XBF);

    hipMemsetAsync(tok_of_slot, 0xFF, MAXS*4, stream);
    hipMemsetAsync(y, 0, (size_t)out_size * 4, stream);

    if (full) {
        gate_kernel<true><<<NTOK/2, 256, 0, stream>>>(x, Wg, tokE, tokW, xbf);
        sort_kernel<<<1, SORT_T, 0, stream>>>(tokE, tokW, aoff, tok_of_slot, w_of_slot);
        conv_kernel<<<2048, 256, 0, stream>>>(W1, wbf, NEXP*I_DIM*H_DIM/8);
        fc1_bf16_kernel<<<NC1*MAXRB, 256, 0, stream>>>(xbf, wbf, aoff, tok_of_slot, h);
        conv_kernel<<<2048, 256, 0, stream>>>(W2, wbf, NEXP*H_DIM*I_DIM/8);
        fc2_kernel_t<0><<<NC2*MAXRB, 256, 0, stream>>>(h, wbf, aoff, tok_of_slot, w_of_slot, y);
    } else if (hasXbf) {
        gate_kernel<true><<<NTOK/2, 256, 0, stream>>>(x, Wg, tokE, tokW, xbf);
        sort_kernel<<<1, SORT_T, 0, stream>>>(tokE, tokW, aoff, tok_of_slot, w_of_slot);
        fc1_kernel_t<0><<<NC1*MAXRB, 256, 0, stream>>>(xbf, W1, aoff, tok_of_slot, h);
        fc2_kernel_t<1><<<NC2*MAXRB, 256, 0, stream>>>(h, W2, aoff, tok_of_slot, w_of_slot, y);
    } else {
        gate_kernel<false><<<NTOK/2, 256, 0, stream>>>(x, Wg, tokE, tokW, nullptr);
        sort_kernel<<<1, SORT_T, 0, stream>>>(tokE, tokW, aoff, tok_of_slot, w_of_slot);
        fc1_kernel_t<1><<<NC1*MAXRB, 256, 0, stream>>>(x, W1, aoff, tok_of_slot, h);
        fc2_kernel_t<1><<<NC2*MAXRB, 256, 0, stream>>>(h, W2, aoff, tok_of_slot, w_of_slot, y);
    }
}